// Round 2
// baseline (238.721 us; speedup 1.0000x reference)
//
#include <hip/hip_runtime.h>
#include <math.h>

// FFF sparse tree forward. B=16384, D_IN=D_OUT=768, DEPTH=11, n_nodes=4095.
//
// One wave per sample; lane owns 12 dims as 3x float4 (lane + j*64 stride).
// Phase 1 (serial tree walk): per level, speculatively prefetch BOTH children
// W1 rows while computing the current f64 dot + butterfly reduce; select the
// winner with a register cndmask. The load latency is thus off the serial
// chain. Sign is readfirstlane'd so node/addresses are wave-uniform SGPRs.
// Phase 2: 12 independent w2 row gathers + fma (no serial dependency), using
// acts + routing bitmask recorded in phase 1.

#define FFF_DEPTH 11
#define FFF_LVLS 12        // depth+1 levels evaluated
#define FFF_D 768
#define FFF_NF4 3          // float4 per lane: 768/4/64
#define FFF_ROWF4 192      // float4 per row

__device__ __forceinline__ double wave_reduce_add_f64(double v) {
#pragma unroll
    for (int m = 32; m > 0; m >>= 1) {
        v += __shfl_xor(v, m, 64);
    }
    return v;
}

__global__ __launch_bounds__(256) void fff_sparse_kernel(
    const float* __restrict__ x,
    const float* __restrict__ w1s,
    const float* __restrict__ w2s,
    float* __restrict__ out,
    int B)
{
    const int wave = threadIdx.x >> 6;
    const int lane = threadIdx.x & 63;
    const int b = blockIdx.x * 4 + wave;
    if (b >= B) return;

    const float4* __restrict__ xf4  = (const float4*)x;
    const float4* __restrict__ w1f4 = (const float4*)w1s;
    const float4* __restrict__ w2f4 = (const float4*)w2s;

    // x row in registers, coalesced.
    const int xb = b * FFF_ROWF4 + lane;
    float4 xv[FFF_NF4];
#pragma unroll
    for (int j = 0; j < FFF_NF4; ++j) xv[j] = xf4[xb + j * 64];

    // Prologue: W1 row of the root.
    float4 cur[FFF_NF4];
#pragma unroll
    for (int j = 0; j < FFF_NF4; ++j) cur[j] = w1f4[lane + j * 64];

    float acts[FFF_LVLS];
    int node = 0;       // wave-uniform (scalar) after readfirstlane of sign
    int bits = 0;       // routing decisions, bit per level

#pragma unroll
    for (int lvl = 0; lvl < FFF_LVLS; ++lvl) {
        // Speculatively prefetch BOTH children W1 rows (addresses don't
        // depend on this level's sign) — overlaps the dot+reduce below.
        float4 s0[FFF_NF4], s1[FFF_NF4];
        if (lvl < FFF_DEPTH) {
            const int c0 = (2 * node + 1) * FFF_ROWF4 + lane;
#pragma unroll
            for (int j = 0; j < FFF_NF4; ++j) s0[j] = w1f4[c0 + j * 64];
#pragma unroll
            for (int j = 0; j < FFF_NF4; ++j) s1[j] = w1f4[c0 + FFF_ROWF4 + j * 64];
        }

        // Routing dot in f64 (sign fidelity vs exact sum), 2 accumulators.
        double p0 = 0.0, p1 = 0.0;
#pragma unroll
        for (int j = 0; j < FFF_NF4; ++j) {
            p0 += (double)xv[j].x * (double)cur[j].x;
            p1 += (double)xv[j].y * (double)cur[j].y;
            p0 += (double)xv[j].z * (double)cur[j].z;
            p1 += (double)xv[j].w * (double)cur[j].w;
        }
        const double p = wave_reduce_add_f64(p0 + p1);

        const float logit = (float)p;
        acts[lvl] = 0.5f * logit * (1.0f + erff(logit * 0.70710678118654752440f));

        const int s = __builtin_amdgcn_readfirstlane(p >= 0.0 ? 1 : 0);
        bits |= s << lvl;
        node = 2 * node + 1 + s;

        if (lvl < FFF_DEPTH) {
#pragma unroll
            for (int j = 0; j < FFF_NF4; ++j) cur[j] = s ? s1[j] : s0[j];
        }
    }

    // Phase 2: 12 independent w2 gathers + fma. Recompute the node sequence
    // from the bitmask (cheap scalar ops); unrolled so all indices static.
    float4 acc[FFF_NF4];
#pragma unroll
    for (int j = 0; j < FFF_NF4; ++j) acc[j] = make_float4(0.f, 0.f, 0.f, 0.f);

    int n2 = 0;
#pragma unroll
    for (int lvl = 0; lvl < FFF_LVLS; ++lvl) {
        const int base = n2 * FFF_ROWF4 + lane;
        const float a = acts[lvl];
        float4 c0 = w2f4[base];
        float4 c1 = w2f4[base + 64];
        float4 c2 = w2f4[base + 128];
        acc[0].x = fmaf(a, c0.x, acc[0].x);
        acc[0].y = fmaf(a, c0.y, acc[0].y);
        acc[0].z = fmaf(a, c0.z, acc[0].z);
        acc[0].w = fmaf(a, c0.w, acc[0].w);
        acc[1].x = fmaf(a, c1.x, acc[1].x);
        acc[1].y = fmaf(a, c1.y, acc[1].y);
        acc[1].z = fmaf(a, c1.z, acc[1].z);
        acc[1].w = fmaf(a, c1.w, acc[1].w);
        acc[2].x = fmaf(a, c2.x, acc[2].x);
        acc[2].y = fmaf(a, c2.y, acc[2].y);
        acc[2].z = fmaf(a, c2.z, acc[2].z);
        acc[2].w = fmaf(a, c2.w, acc[2].w);
        n2 = 2 * n2 + 1 + ((bits >> lvl) & 1);
    }

    float4* __restrict__ of4 = (float4*)out;
    const int ob = b * FFF_ROWF4 + lane;
#pragma unroll
    for (int j = 0; j < FFF_NF4; ++j) of4[ob + j * 64] = acc[j];
}

extern "C" void kernel_launch(void* const* d_in, const int* in_sizes, int n_in,
                              void* d_out, int out_size, void* d_ws, size_t ws_size,
                              hipStream_t stream) {
    const float* x   = (const float*)d_in[0];
    const float* w1s = (const float*)d_in[1];
    const float* w2s = (const float*)d_in[2];
    float* out = (float*)d_out;

    const int B = out_size / FFF_D;          // 16384
    const int blocks = (B + 3) / 4;          // 4 waves (samples) per block

    fff_sparse_kernel<<<blocks, 256, 0, stream>>>(x, w1s, w2s, out, B);
}